// Round 6
// baseline (341.815 us; speedup 1.0000x reference)
//
#include <hip/hip_runtime.h>
#include <hip/hip_bf16.h>
#include <stdint.h>

typedef __bf16 bf16;
typedef __bf16 bf16x8 __attribute__((ext_vector_type(8)));
typedef float  f32x4  __attribute__((ext_vector_type(4)));

#define BM 128
#define BN 64
#define BK 64
#define E  512
#define SB 4112            // per-batch extended row stride (4098 valid + 14 pad)
#define M1 (8 * SB)        // 32896 = 128 * 257 extended rows
#define M2 32768           // output rows

__device__ __forceinline__ void gl_lds_16(const bf16* g, bf16* l) {
    __builtin_amdgcn_global_load_lds(
        (__attribute__((address_space(1))) void*)g,
        (__attribute__((address_space(3))) void*)l,
        16, 0, 0);
}

// Structure notes (measured rounds 0-5):
//  - 2-phase stage->sync->compute->sync, BM=128/BN=64/BK=64, XCD-grouped 1D
//    grid = best-measured form (232 us total).  Schedule surgery (vmcnt rings,
//    256^2 deep-cover) regressed ~70% -- latency-bound kernels live off TLP.
//  - This round: FUSE the 5-tap Gaussian prefilter into gemm1's A-staging
//    (filter commutes with the channel projection).  Kills the prefilter
//    dispatch and the vg write+read (~68 MB HBM); filter FLOPs are trivial
//    (~168 MFLOP device-wide) and hide under gemm1's idle VALU (was ~6%).
//    A-staging becomes reg-staged (load fp32 halo rows, fma, cvt, ds_write
//    directly swizzled); B keeps global_load_lds and is issued first.

// ------- GEMM1 (fused filter): C[m,n] = sum_k VG[m,k]*B[n,k], bf16 out -------
// VG[m,k] = sum_j filt[j] * vals[b, (m - b*SB) - 3 + j, k],  b = m / SB,
// taps outside [0,4096) contribute zero (matches reference zero-padding).
__global__ __launch_bounds__(256, 4)
void gemm1_fused(const float* __restrict__ vals, const bf16* __restrict__ Bm,
                 bf16* __restrict__ C)
{
    __shared__ bf16 As[BM * BK];          // 16 KB
    __shared__ bf16 Bs[BN * BK];          // 8 KB

    const int tid  = threadIdx.x;
    const int nq   = gridDim.x >> 3;                  // 2056/8 = 257
    const int orig = (blockIdx.x & 7) * nq + (blockIdx.x >> 3);
    const int bm   = orig >> 3;                       // 0..256
    const int bn   = orig & 7;                        // 0..7
    const int wave = tid >> 6;
    const int lane = tid & 63;
    const int wm   = wave >> 1;                       // 0..1 (64 rows)
    const int wn   = wave & 1;                        // 0..1 (32 cols)

    // B staging (global_load_lds, pre-swizzled source col, linear dest)
    const int srow = tid >> 3;                        // 0..31
    const int scol = (((tid & 7) ^ (srow & 7)) << 3);
    const size_t b_off = (size_t)(bn * BN + srow) * E + scol;
    const int    l_off = tid * 8;

    // A staging (reg-staged filter): thread covers chunk ach (8 ch) of 4 rows
    const int ach = tid & 7;                          // chunk 0..7
    const int arg = tid >> 3;                         // row group 0..31
    int  sbase[4];                                    // V-row of tap j=0
    const float* vb[4];                               // batch base ptr
#pragma unroll
    for (int u = 0; u < 4; ++u) {
        const int m = bm * BM + arg * 4 + u;          // extended row
        const int b = m / SB;
        sbase[u] = (m - b * SB) - 3;
        vb[u] = vals + (size_t)b * 4096 * E + ach * 8;
    }

    const float filt[5] = {0.05399096651318806f, 0.24197072451914337f,
                           0.3989422804014327f,
                           0.24197072451914337f, 0.05399096651318806f};

    f32x4 acc[4][2] = {};
    const int fr = lane & 15;
    const int q  = lane >> 4;

    for (int k0 = 0; k0 < E; k0 += BK) {
        // issue async B loads first; they land while we filter A
#pragma unroll
        for (int c = 0; c < 2; ++c)
            gl_lds_16(Bm + b_off + (size_t)(c * 32) * E + k0, Bs + c * 2048 + l_off);

        // filter 4 rows x 8 channels into swizzled LDS
#pragma unroll
        for (int u = 0; u < 4; ++u) {
            float a8[8] = {0.f, 0.f, 0.f, 0.f, 0.f, 0.f, 0.f, 0.f};
#pragma unroll
            for (int j = 0; j < 5; ++j) {
                const int sp = sbase[u] + j;
                if (sp >= 0 && sp < 4096) {
                    const f32x4* p = (const f32x4*)(vb[u] + (size_t)sp * E + k0);
                    const f32x4 x0 = p[0], x1 = p[1];
                    const float w = filt[j];
                    a8[0] += w * x0[0]; a8[1] += w * x0[1];
                    a8[2] += w * x0[2]; a8[3] += w * x0[3];
                    a8[4] += w * x1[0]; a8[5] += w * x1[1];
                    a8[6] += w * x1[2]; a8[7] += w * x1[3];
                }
            }
            bf16x8 o;
#pragma unroll
            for (int d = 0; d < 8; ++d) o[d] = (bf16)a8[d];
            const int r = arg * 4 + u;
            *(bf16x8*)(As + r * BK + ((ach ^ (r & 7)) << 3)) = o;
        }
        __syncthreads();

#pragma unroll
        for (int t = 0; t < 2; ++t) {                 // two 32-wide k sub-steps
            bf16x8 af[4], bfr[2];
#pragma unroll
            for (int i = 0; i < 4; ++i) {
                const int Ra = wm * 64 + i * 16 + fr;
                const int c  = t * 4 + q;
                af[i] = *(const bf16x8*)(As + Ra * BK + ((c ^ (Ra & 7)) << 3));
            }
#pragma unroll
            for (int j = 0; j < 2; ++j) {
                const int Rb = wn * 32 + j * 16 + fr;
                const int c  = t * 4 + q;
                bfr[j] = *(const bf16x8*)(Bs + Rb * BK + ((c ^ (Rb & 7)) << 3));
            }
#pragma unroll
            for (int i = 0; i < 4; ++i)
#pragma unroll
                for (int j = 0; j < 2; ++j)
                    acc[i][j] = __builtin_amdgcn_mfma_f32_16x16x32_bf16(af[i], bfr[j], acc[i][j], 0, 0, 0);
        }
        __syncthreads();
    }

    const int crow = (lane >> 4) << 2;
    const int ccol = lane & 15;
    const int row0 = bm * BM + wm * 64 + crow;
    const int col0 = bn * BN + wn * 32 + ccol;
#pragma unroll
    for (int i = 0; i < 4; ++i)
#pragma unroll
        for (int j = 0; j < 2; ++j)
#pragma unroll
            for (int r = 0; r < 4; ++r)
                C[(size_t)(row0 + i * 16 + r) * E + (col0 + j * 16)] = (bf16)acc[i][j][r];
}

// ------- GEMM2: A gathered with per-head row shift; fp32 out ------------------
// A2[m=(b,s), k] = P[b*SB + s + 1 + sh(k>>6), k]; sh uniform per K-iter
// (BK=64 == one head).  Unchanged from round 5 (measured good).
__global__ __launch_bounds__(256)
void gemm2_gather(const bf16* __restrict__ P, const bf16* __restrict__ Bm,
                  float* __restrict__ C)
{
    __shared__ bf16 As[BM * BK];
    __shared__ bf16 Bs[BN * BK];

    const int tid  = threadIdx.x;
    const int nq   = gridDim.x >> 3;                  // 2048/8 = 256
    const int orig = (blockIdx.x & 7) * nq + (blockIdx.x >> 3);
    const int bm   = orig >> 3;                       // 0..255
    const int bn   = orig & 7;                        // 0..7
    const int wave = tid >> 6;
    const int lane = tid & 63;
    const int wm   = wave >> 1;
    const int wn   = wave & 1;

    const int srow = tid >> 3;                        // 0..31
    const int scol = (((tid & 7) ^ (srow & 7)) << 3);
    const size_t b_off = (size_t)(bn * BN + srow) * E + scol;
    const int    l_off = tid * 8;

    f32x4 acc[4][2] = {};
    const int fr = lane & 15;
    const int q  = lane >> 4;

    for (int k0 = 0; k0 < E; k0 += BK) {
        const int h3 = (k0 >> 6) & 3;                       // head pattern %4
        const int sh = (h3 == 1) ? -1 : (h3 == 2) ? 1 : 0;  // wave-uniform
#pragma unroll
        for (int c = 0; c < 4; ++c) {
            const int m = bm * BM + c * 32 + srow;          // output row staged
            const int prow = (m >> 12) * SB + (m & 4095) + 1 + sh;
            gl_lds_16(P + (size_t)prow * E + k0 + scol, As + c * 2048 + l_off);
        }
#pragma unroll
        for (int c = 0; c < 2; ++c)
            gl_lds_16(Bm + b_off + (size_t)(c * 32) * E + k0, Bs + c * 2048 + l_off);
        __syncthreads();

#pragma unroll
        for (int t = 0; t < 2; ++t) {
            bf16x8 af[4], bfr[2];
#pragma unroll
            for (int i = 0; i < 4; ++i) {
                const int Ra = wm * 64 + i * 16 + fr;
                const int c  = t * 4 + q;
                af[i] = *(const bf16x8*)(As + Ra * BK + ((c ^ (Ra & 7)) << 3));
            }
#pragma unroll
            for (int j = 0; j < 2; ++j) {
                const int Rb = wn * 32 + j * 16 + fr;
                const int c  = t * 4 + q;
                bfr[j] = *(const bf16x8*)(Bs + Rb * BK + ((c ^ (Rb & 7)) << 3));
            }
#pragma unroll
            for (int i = 0; i < 4; ++i)
#pragma unroll
                for (int j = 0; j < 2; ++j)
                    acc[i][j] = __builtin_amdgcn_mfma_f32_16x16x32_bf16(af[i], bfr[j], acc[i][j], 0, 0, 0);
        }
        __syncthreads();
    }

    const int crow = (lane >> 4) << 2;
    const int ccol = lane & 15;
    const int row0 = bm * BM + wm * 64 + crow;
    const int col0 = bn * BN + wn * 32 + ccol;
#pragma unroll
    for (int i = 0; i < 4; ++i)
#pragma unroll
        for (int j = 0; j < 2; ++j)
#pragma unroll
            for (int r = 0; r < 4; ++r)
                C[(size_t)(row0 + i * 16 + r) * E + (col0 + j * 16)] = acc[i][j][r];
}

// ------- weight convert: both 512x512 fp32 matrices -> bf16 -------------------
__global__ __launch_bounds__(256)
void cvt_weights(const float* __restrict__ w_in, const float* __restrict__ w_out,
                 bf16* __restrict__ win_b, bf16* __restrict__ wout_b)
{
    const int i = blockIdx.x * 256 + threadIdx.x;      // [0, 65536)
    const int half = (E * E) / 8;                      // 32768
    const float* src = (i < half) ? w_in : w_out;
    bf16* dst        = (i < half) ? win_b : wout_b;
    const int k = (i < half) ? i : i - half;
    const f32x4* p = (const f32x4*)src + 2 * (size_t)k;
    f32x4 a = p[0], bq = p[1];
    bf16x8 o;
    o[0] = (bf16)a[0];  o[1] = (bf16)a[1];  o[2] = (bf16)a[2];  o[3] = (bf16)a[3];
    o[4] = (bf16)bq[0]; o[5] = (bf16)bq[1]; o[6] = (bf16)bq[2]; o[7] = (bf16)bq[3];
    *((bf16x8*)dst + k) = o;
}

extern "C" void kernel_launch(void* const* d_in, const int* in_sizes, int n_in,
                              void* d_out, int out_size, void* d_ws, size_t ws_size,
                              hipStream_t stream)
{
    const float* values = (const float*)d_in[0];
    // d_in[1]=keys, d_in[2]=queries: unused by the reference path (no QK^T)
    const float* w_in   = (const float*)d_in[3];
    const float* w_out  = (const float*)d_in[4];
    float* out = (float*)d_out;

    // workspace: weights 1 MB + P 33.7 MB (vg eliminated by the fusion)
    bf16* win_b  = (bf16*)d_ws;                 // 512*512
    bf16* wout_b = win_b + E * E;               // 512*512
    bf16* Pbuf   = wout_b + E * E;              // M1*E

    cvt_weights<<<(2 * E * E / 8) / 256, 256, 0, stream>>>(w_in, w_out, win_b, wout_b);

    // grids: (M/128) x 8 column-blocks, 8-divisible -> clean XCD grouping
    gemm1_fused<<<(M1 / BM) * 8, 256, 0, stream>>>(values, win_b, Pbuf);
    gemm2_gather<<<(M2 / BM) * 8, 256, 0, stream>>>(Pbuf, wout_b, out);
}

// Round 7
// 240.853 us; speedup vs baseline: 1.4192x; 1.4192x over previous
//
#include <hip/hip_runtime.h>
#include <hip/hip_bf16.h>
#include <stdint.h>

typedef __bf16 bf16;
typedef __bf16 bf16x8 __attribute__((ext_vector_type(8)));
typedef float  f32x4  __attribute__((ext_vector_type(4)));

#define BM 128
#define BN 64
#define BK 64
#define E  512
#define SB 4112            // per-batch extended row stride (4098 valid + 14 pad)
#define M1 (8 * SB)        // 32896 = 128 * 257 extended rows
#define M2 32768           // output rows

__device__ __forceinline__ void gl_lds_16(const bf16* g, bf16* l) {
    __builtin_amdgcn_global_load_lds(
        (__attribute__((address_space(1))) void*)g,
        (__attribute__((address_space(3))) void*)l,
        16, 0, 0);
}

// Structure notes (measured rounds 0-6):
//  - BEST MEASURED: this exact form, 232.0 us (round 5).
//  - 2-phase stage->sync->compute->sync, BM=128/BN=64/BK=64, XCD-grouped 1D
//    grid, async global_load_lds staging, XOR chunk swizzle (linear gl_lds
//    dest + pre-swizzled global col + swizzled ds_read) -> 0 bank conflicts.
//  - REFUTED by measurement, do not retry:
//    * 256^2 tile, 1 block/CU, full-tile prefetch (r2: 46 us/gemm) -- sync
//      drains vmcnt(0); no TLP to hide it.
//    * 3-buffer counted-vmcnt ring (r4: 48 us/gemm) -- schedule surgery kills
//      the TLP these latency-bound kernels live off (guide m131-m141).
//    * Fusing the 5-tap filter into gemm1 A-staging (r6: 170 us) -- filter
//      work replicated x8 across bn-siblings + 40-load dependent reg-staging
//      chain on the K-loop critical path (MfmaUtil 4%, HBM 5%).

// ---------------- GEMM1: C[m,n] = sum_k A[m,k]*B[n,k], bf16 out ----------------
__global__ __launch_bounds__(256)
void gemm_bt_bf16(const bf16* __restrict__ A, const bf16* __restrict__ Bm,
                  bf16* __restrict__ C, int M, int N, int K)
{
    __shared__ bf16 As[BM * BK];          // 16 KB
    __shared__ bf16 Bs[BN * BK];          // 8 KB

    const int tid  = threadIdx.x;
    // XCD-grouping: HW assigns xcd ~ bid%8; give each XCD a contiguous run of
    // original ids so the 8 bn-siblings of each bm stay on one L2.
    const int nq   = gridDim.x >> 3;                  // 2056/8 = 257
    const int orig = (blockIdx.x & 7) * nq + (blockIdx.x >> 3);
    const int bm   = orig >> 3;                       // 0..256
    const int bn   = orig & 7;                        // 0..7
    const int wave = tid >> 6;
    const int lane = tid & 63;
    const int wm   = wave >> 1;                       // 0..1 (64 rows)
    const int wn   = wave & 1;                        // 0..1 (32 cols)

    const int srow = tid >> 3;                        // 0..31
    const int scol = (((tid & 7) ^ (srow & 7)) << 3); // swizzled source col
    const size_t a_off = (size_t)(bm * BM + srow) * K + scol;
    const size_t b_off = (size_t)(bn * BN + srow) * K + scol;
    const int    l_off = tid * 8;                     // linear dest: lane*16B

    f32x4 acc[4][2] = {};
    const int fr = lane & 15;
    const int q  = lane >> 4;

    for (int k0 = 0; k0 < K; k0 += BK) {
#pragma unroll
        for (int c = 0; c < 4; ++c)                   // A: 4 calls x 32 rows
            gl_lds_16(A + a_off + (size_t)(c * 32) * K + k0, As + c * 2048 + l_off);
#pragma unroll
        for (int c = 0; c < 2; ++c)                   // B: 2 calls x 32 rows
            gl_lds_16(Bm + b_off + (size_t)(c * 32) * K + k0, Bs + c * 2048 + l_off);
        __syncthreads();

#pragma unroll
        for (int t = 0; t < 2; ++t) {                 // two 32-wide k sub-steps
            bf16x8 af[4], bfr[2];
#pragma unroll
            for (int i = 0; i < 4; ++i) {
                const int Ra = wm * 64 + i * 16 + fr;
                const int c  = t * 4 + q;
                af[i] = *(const bf16x8*)(As + Ra * BK + ((c ^ (Ra & 7)) << 3));
            }
#pragma unroll
            for (int j = 0; j < 2; ++j) {
                const int Rb = wn * 32 + j * 16 + fr;
                const int c  = t * 4 + q;
                bfr[j] = *(const bf16x8*)(Bs + Rb * BK + ((c ^ (Rb & 7)) << 3));
            }
#pragma unroll
            for (int i = 0; i < 4; ++i)
#pragma unroll
                for (int j = 0; j < 2; ++j)
                    acc[i][j] = __builtin_amdgcn_mfma_f32_16x16x32_bf16(af[i], bfr[j], acc[i][j], 0, 0, 0);
        }
        __syncthreads();
    }

    const int crow = (lane >> 4) << 2;
    const int ccol = lane & 15;
    const int row0 = bm * BM + wm * 64 + crow;
    const int col0 = bn * BN + wn * 32 + ccol;
#pragma unroll
    for (int i = 0; i < 4; ++i)
#pragma unroll
        for (int j = 0; j < 2; ++j)
#pragma unroll
            for (int r = 0; r < 4; ++r)
                C[(size_t)(row0 + i * 16 + r) * N + (col0 + j * 16)] = (bf16)acc[i][j][r];
}

// ------- GEMM2: A gathered with per-head row shift; fp32 out ------------------
// A2[m=(b,s), k] = P[b*SB + s + 1 + sh(k>>6), k]; sh uniform per K-iter
// (BK=64 == one head).
__global__ __launch_bounds__(256)
void gemm2_gather(const bf16* __restrict__ P, const bf16* __restrict__ Bm,
                  float* __restrict__ C)
{
    __shared__ bf16 As[BM * BK];
    __shared__ bf16 Bs[BN * BK];

    const int tid  = threadIdx.x;
    const int nq   = gridDim.x >> 3;                  // 2048/8 = 256
    const int orig = (blockIdx.x & 7) * nq + (blockIdx.x >> 3);
    const int bm   = orig >> 3;                       // 0..255
    const int bn   = orig & 7;                        // 0..7
    const int wave = tid >> 6;
    const int lane = tid & 63;
    const int wm   = wave >> 1;
    const int wn   = wave & 1;

    const int srow = tid >> 3;                        // 0..31
    const int scol = (((tid & 7) ^ (srow & 7)) << 3);
    const size_t b_off = (size_t)(bn * BN + srow) * E + scol;
    const int    l_off = tid * 8;

    f32x4 acc[4][2] = {};
    const int fr = lane & 15;
    const int q  = lane >> 4;

    for (int k0 = 0; k0 < E; k0 += BK) {
        const int h3 = (k0 >> 6) & 3;                       // head pattern %4
        const int sh = (h3 == 1) ? -1 : (h3 == 2) ? 1 : 0;  // wave-uniform
#pragma unroll
        for (int c = 0; c < 4; ++c) {
            const int m = bm * BM + c * 32 + srow;          // output row staged
            const int prow = (m >> 12) * SB + (m & 4095) + 1 + sh;
            gl_lds_16(P + (size_t)prow * E + k0 + scol, As + c * 2048 + l_off);
        }
#pragma unroll
        for (int c = 0; c < 2; ++c)
            gl_lds_16(Bm + b_off + (size_t)(c * 32) * E + k0, Bs + c * 2048 + l_off);
        __syncthreads();

#pragma unroll
        for (int t = 0; t < 2; ++t) {
            bf16x8 af[4], bfr[2];
#pragma unroll
            for (int i = 0; i < 4; ++i) {
                const int Ra = wm * 64 + i * 16 + fr;
                const int c  = t * 4 + q;
                af[i] = *(const bf16x8*)(As + Ra * BK + ((c ^ (Ra & 7)) << 3));
            }
#pragma unroll
            for (int j = 0; j < 2; ++j) {
                const int Rb = wn * 32 + j * 16 + fr;
                const int c  = t * 4 + q;
                bfr[j] = *(const bf16x8*)(Bs + Rb * BK + ((c ^ (Rb & 7)) << 3));
            }
#pragma unroll
            for (int i = 0; i < 4; ++i)
#pragma unroll
                for (int j = 0; j < 2; ++j)
                    acc[i][j] = __builtin_amdgcn_mfma_f32_16x16x32_bf16(af[i], bfr[j], acc[i][j], 0, 0, 0);
        }
        __syncthreads();
    }

    const int crow = (lane >> 4) << 2;
    const int ccol = lane & 15;
    const int row0 = bm * BM + wm * 64 + crow;
    const int col0 = bn * BN + wn * 32 + ccol;
#pragma unroll
    for (int i = 0; i < 4; ++i)
#pragma unroll
        for (int j = 0; j < 2; ++j)
#pragma unroll
            for (int r = 0; r < 4; ++r)
                C[(size_t)(row0 + i * 16 + r) * E + (col0 + j * 16)] = acc[i][j][r];
}

// ------- prep: weight-convert blocks [0,256) + prefilter blocks [256,1284) ----
// prefilter: VG[b, r, e] = sum_j filt[j] * values[b, r-1+j-2, e], 8 rows/thread
// sliding window (1.5x re-read).  cvt: both 512x512 fp32 -> bf16.
__global__ __launch_bounds__(256)
void prep(const float* __restrict__ vals, const float* __restrict__ w_in,
          const float* __restrict__ w_out, bf16* __restrict__ vg,
          bf16* __restrict__ win_b, bf16* __restrict__ wout_b)
{
    const int tid = threadIdx.x;
    const int blk = blockIdx.x;

    if (blk < 256) {                                   // weight convert
        const int i = blk * 256 + tid;                 // [0, 65536)
        const int half = (E * E) / 8;                  // 32768
        const float* src = (i < half) ? w_in : w_out;
        bf16* dst        = (i < half) ? win_b : wout_b;
        const int k = (i < half) ? i : i - half;
        const f32x4* p = (const f32x4*)src + 2 * (size_t)k;
        f32x4 a = p[0], bq = p[1];
        bf16x8 o;
        o[0] = (bf16)a[0];  o[1] = (bf16)a[1];  o[2] = (bf16)a[2];  o[3] = (bf16)a[3];
        o[4] = (bf16)bq[0]; o[5] = (bf16)bq[1]; o[6] = (bf16)bq[2]; o[7] = (bf16)bq[3];
        *((bf16x8*)dst + k) = o;
        return;
    }

    const int e8   = tid & 63;                         // channel chunk (8 floats)
    const int gidx = (blk - 256) * 4 + (tid >> 6);     // row group [0, M1/8)
    const int m0   = gidx << 3;                        // first extended row
    const int b    = m0 / SB;                          // group never straddles batch
    const int r0   = m0 - b * SB;                      // [0, 4112)

    const float filt[5] = {0.05399096651318806f, 0.24197072451914337f,
                           0.3989422804014327f,
                           0.24197072451914337f, 0.05399096651318806f};

    float acc[8][8];
#pragma unroll
    for (int t = 0; t < 8; ++t)
#pragma unroll
        for (int d = 0; d < 8; ++d) acc[t][d] = 0.f;

    const float* bbase = vals + (size_t)b * 4096 * E + e8 * 8;
#pragma unroll
    for (int u = 0; u < 12; ++u) {                     // inputs sp = r0-3 .. r0+8
        const int sp = r0 - 3 + u;
        if (sp >= 0 && sp < 4096) {
            const f32x4* p = (const f32x4*)(bbase + (size_t)sp * E);
            const f32x4 x0 = p[0], x1 = p[1];
            const float x[8] = {x0[0], x0[1], x0[2], x0[3],
                                x1[0], x1[1], x1[2], x1[3]};
#pragma unroll
            for (int t = 0; t < 8; ++t) {              // out row r0+t needs j = u-t
                const int j = u - t;
                if (j >= 0 && j < 5) {
                    const float w = filt[j];
#pragma unroll
                    for (int d = 0; d < 8; ++d) acc[t][d] += w * x[d];
                }
            }
        }
    }
#pragma unroll
    for (int t = 0; t < 8; ++t) {
        bf16x8 o;
#pragma unroll
        for (int d = 0; d < 8; ++d) o[d] = (bf16)acc[t][d];
        *((bf16x8*)vg + (size_t)(m0 + t) * 64 + e8) = o;
    }
}

extern "C" void kernel_launch(void* const* d_in, const int* in_sizes, int n_in,
                              void* d_out, int out_size, void* d_ws, size_t ws_size,
                              hipStream_t stream)
{
    const float* values = (const float*)d_in[0];
    // d_in[1]=keys, d_in[2]=queries: unused by the reference path (no QK^T)
    const float* w_in   = (const float*)d_in[3];
    const float* w_out  = (const float*)d_in[4];
    float* out = (float*)d_out;

    // workspace: weights 1 MB + VG 33.7 MB + P 33.7 MB ~= 68.4 MB
    bf16* win_b  = (bf16*)d_ws;                 // 512*512
    bf16* wout_b = win_b + E * E;               // 512*512
    bf16* vg     = wout_b + E * E;              // M1*E
    bf16* Pbuf   = vg + (size_t)M1 * E;         // M1*E

    prep<<<256 + M1 / 32, 256, 0, stream>>>(values, w_in, w_out, vg, win_b, wout_b);

    // grids: (M/128) x 8 column-blocks, 8-divisible -> clean XCD grouping
    gemm_bt_bf16<<<(M1 / BM) * 8, 256, 0, stream>>>(vg, win_b, Pbuf, M1, E, E);
    gemm2_gather<<<(M2 / BM) * 8, 256, 0, stream>>>(Pbuf, wout_b, out);
}